// Round 11
// baseline (256.305 us; speedup 1.0000x reference)
//
#include <hip/hip_runtime.h>
#include <hip/hip_bf16.h>

// ---------------------------------------------------------------------------
// RoIHead 5-kernel pipeline (R10 champion) with roipool rewritten:
//  - division-free 2D load loop
//  - bin results staged in LDS [16][49] then written as ONE coalesced block
//    copy (784 contiguous bf16 per block) instead of 3.2M scattered 2B stores
// Everything else byte-identical to R10 (253.5 us).
// Model: total = C(~95us fixed) + kernels(~143) + ~3us/launch. Attacking the
// ~25us gap between smalls' measured 59us and their ~33us arithmetic floor.
// ---------------------------------------------------------------------------

typedef __attribute__((ext_vector_type(8))) short bf16x8;
typedef __attribute__((ext_vector_type(4))) float f32x4;
typedef __attribute__((ext_vector_type(4))) short s16x4;

typedef const __attribute__((address_space(1))) void gvoid;
typedef __attribute__((address_space(3))) void lvoid;
#define GLD_LDS16(gp, lp) __builtin_amdgcn_global_load_lds((gvoid*)(gp), (lvoid*)(lp), 16, 0, 0)

#define WAITV8() { asm volatile("s_waitcnt vmcnt(8)" ::: "memory"); __builtin_amdgcn_sched_barrier(0); }
#define WAITV0() { asm volatile("s_waitcnt vmcnt(0)" ::: "memory"); __builtin_amdgcn_sched_barrier(0); }
#define BAR() { __builtin_amdgcn_sched_barrier(0); __builtin_amdgcn_s_barrier(); __builtin_amdgcn_sched_barrier(0); }

static __device__ __forceinline__ short f2bf(float f) {   // RNE f32->bf16
  unsigned u = __builtin_bit_cast(unsigned, f);
  u += 0x7fffu + ((u >> 16) & 1u);
  return (short)(u >> 16);
}

// ---------------- K1: ROI pool -> A bf16 [128][25088] ----------------
// block = (cg, r): 16 channels x one ROI. Lanes i=0..15 per channel.
__global__ __launch_bounds__(256) void roipool_kernel(
    const float* __restrict__ x, const float* __restrict__ rois,
    __hip_bfloat16* __restrict__ A) {
  const int cg = blockIdx.x;      // 0..31, 16 channels each
  const int r  = blockIdx.y;      // 0..127
  const float y1 = rois[r*4+0], x1 = rois[r*4+1], y2 = rois[r*4+2], x2 = rois[r*4+3];
  const int h0 = (int)(y1 * 0.0625f);
  const int h1 = (int)(y2 * 0.0625f) + 1;
  const int w0 = (int)(x1 * 0.0625f);
  const int w1 = (int)(x2 * 0.0625f) + 1;
  const int Hh = h1 - h0, Ww = w1 - w0;        // <= 17 each
  __shared__ float tile[16][300];
  __shared__ short obuf[16][49];               // bin outputs, (c,b) layout
  const int cl = threadIdx.x >> 4, i = threadIdx.x & 15;
  const int c = cg*16 + cl;
  const float* xc = x + c*1850 + h0*50 + w0;   // x: [512][37][50]
  // division-free load: rows sequential, cols lane-strided
  for (int rr = 0; rr < Hh; ++rr)
    for (int cc = i; cc < Ww; cc += 16)
      tile[cl][rr*Ww + cc] = xc[rr*50 + cc];
  __syncthreads();
  // bins (PyTorch AdaptiveMaxPool2d: [floor(i*L/7), ceil((i+1)*L/7)) )
  for (int b = i; b < 49; b += 16) {
    int hb = b / 7, wb = b - hb*7;             // const-7 div -> magic mul
    int rs = (hb*Hh)/7,  re = ((hb+1)*Hh + 6)/7;
    int cs = (wb*Ww)/7,  ce = ((wb+1)*Ww + 6)/7;
    float m = -3.402823466e38f;
    for (int rr2 = rs; rr2 < re; ++rr2)
      for (int cc2 = cs; cc2 < ce; ++cc2)
        m = fmaxf(m, tile[cl][rr2*Ww + cc2]);
    obuf[cl][b] = f2bf(m);
  }
  __syncthreads();
  // coalesced write: this block owns A[r, cg*784 .. cg*784+784) (contiguous)
  {
    const int t = threadIdx.x;
    int* dst = (int*)((short*)A + (size_t)r*25088 + cg*784);  // 4B-aligned (784 even)
    const int* src = (const int*)&obuf[0][0];                 // 392 dwords
    if (t < 196) {
      int2 v = ((const int2*)src)[t];
      ((int2*)dst)[t] = v;
    }
  }
}

// ---------------- K2/K4: MFMA split-K GEMM (R2 body) ----------------
__global__ __launch_bounds__(256) void gemm_kernel(
    const __hip_bfloat16* __restrict__ A,  // [128][K] bf16
    const float* __restrict__ B,           // [K][4096] f32
    float* __restrict__ part,              // [8][128][4096] f32
    int K, int KC) {
  __shared__ short lA[2][8192];    // 2 x 16 KB
  __shared__ float lB[2][4096];    // 2 x 16 KB
  const int t = threadIdx.x;
  const int w = t >> 6, l = t & 63;
  const int bid = blockIdx.x;
  const int s  = bid & 7;          // XCD-locality: same s stays on one XCD
  const int nb = bid >> 3;
  const int kc0 = s * KC;
  const int Arow_bytes = K * 2;

  int aoff[4], boff[4];
#pragma unroll
  for (int p = 0; p < 4; ++p) {
    int o = (p*256 + t) * 16;                     // linear LDS byte offset
    int oa = o ^ (((o >> 7) & 7) << 4);           // inverse A swizzle (involution)
    aoff[p] = (oa >> 7) * Arow_bytes + (oa & 127);
    int ob = o ^ (((o >> 11) & 1) << 6);          // inverse B swizzle (involution)
    boff[p] = (ob >> 8) * 16384 + (ob & 255);
  }
  const int r15 = l & 15, kh = l >> 4;
  const int xa = (r15 & 7) << 4;
  const int aoj0 = r15*128 + ((kh*16) ^ xa);
  const int aoj1 = r15*128 + (((64) + kh*16) ^ xa);
  const int bo0  = ((kh*8)*256 + (w*16 + r15)*4) ^ ((kh & 1) << 6);

  const char* Ak = (const char*)A + kc0*2;
  const char* Bk = (const char*)B + (size_t)kc0*16384 + nb*256;

  f32x4 acc[8] = {};
  const int steps = KC >> 6;
  int cur = 0;

#pragma unroll
  for (int p = 0; p < 4; ++p) {
    GLD_LDS16(Ak + aoff[p], (char*)lA[0] + (p*256 + w*64)*16);
    GLD_LDS16(Bk + boff[p], (char*)lB[0] + (p*256 + w*64)*16);
  }
  Ak += 128; Bk += 64 * 16384;

  for (int st = 0; st < steps; ++st) {
    if (st + 1 < steps) {
      char* dA = (char*)lA[cur ^ 1];
      char* dB = (char*)lB[cur ^ 1];
#pragma unroll
      for (int p = 0; p < 4; ++p) {
        GLD_LDS16(Ak + aoff[p], dA + (p*256 + w*64)*16);
        GLD_LDS16(Bk + boff[p], dB + (p*256 + w*64)*16);
      }
      Ak += 128; Bk += 64 * 16384;
      WAITV8();
    } else {
      WAITV0();
    }
    BAR();
    const char* lAb = (const char*)lA[cur];
    const char* lBb = (const char*)lB[cur];
#pragma unroll
    for (int j = 0; j < 2; ++j) {
      const int ao = j ? aoj1 : aoj0;
      const int bo = (j ? 8192 : 0) + bo0;
      float bf[8];
#pragma unroll
      for (int i2 = 0; i2 < 8; ++i2)
        bf[i2] = *(const float*)(lBb + bo + i2*256);
      bf16x8 bfrag;
#pragma unroll
      for (int i2 = 0; i2 < 8; ++i2) bfrag[i2] = f2bf(bf[i2]);
#pragma unroll
      for (int mf = 0; mf < 8; ++mf) {
        bf16x8 afrag = *(const bf16x8*)(lAb + mf*2048 + ao);
        acc[mf] = __builtin_amdgcn_mfma_f32_16x16x32_bf16(afrag, bfrag, acc[mf], 0, 0, 0);
      }
    }
    BAR();
    cur ^= 1;
  }
  // C/D: col = lane&15, row = (lane>>4)*4 + q
  const int n = nb*64 + w*16 + r15;
  float* prow = part + (size_t)s*524288 + n;
#pragma unroll
  for (int mf = 0; mf < 8; ++mf) {
    int m0 = mf*16 + kh*4;
#pragma unroll
    for (int q = 0; q < 4; ++q)
      prow[(m0 + q)*4096] = acc[mf][q];
  }
}

// ---------------- K3: reduce partials + b1 + relu -> fc6 bf16 ----------------
__global__ __launch_bounds__(256) void reduce_kernel(
    const float* __restrict__ part, const float* __restrict__ bias,
    short* __restrict__ outp) {
  const int idx = (blockIdx.x*256 + threadIdx.x) * 4;   // over 128*4096
  f32x4 sum = {};
#pragma unroll
  for (int s2 = 0; s2 < 8; ++s2)
    sum += *(const f32x4*)(part + (size_t)s2*524288 + idx);
  sum += *(const f32x4*)(bias + (idx & 4095));
  s16x4 o;
#pragma unroll
  for (int q = 0; q < 4; ++q) o[q] = f2bf(fmaxf(sum[q], 0.f));
  *(s16x4*)(outp + idx) = o;
}

// ---------------- K5: reduce partials + b2 + relu -> row; row @ {Wloc,Wscore}
__global__ __launch_bounds__(512) void final_kernel(
    const float* __restrict__ part, const float* __restrict__ b2,
    const float* __restrict__ Wloc, const float* __restrict__ bloc,
    const float* __restrict__ Wscore, const float* __restrict__ bscore,
    float* __restrict__ out) {
  __shared__ float row[4096];
  __shared__ float psum[4][128];
  const int r = blockIdx.x, t = threadIdx.x;
  for (int ci = t; ci < 1024; ci += 512) {
    f32x4 sum = {};
#pragma unroll
    for (int s2 = 0; s2 < 8; ++s2)
      sum += *(const f32x4*)(part + (size_t)s2*524288 + r*4096 + ci*4);
    sum += *(const f32x4*)(b2 + ci*4);
    f32x4 o;
#pragma unroll
    for (int q = 0; q < 4; ++q) o[q] = fmaxf(sum[q], 0.f);
    *(f32x4*)&row[ci*4] = o;
  }
  __syncthreads();
  const int c = t & 127, ks = t >> 7;
  float acc = 0.f;
  if (c < 105) {
    const float* W; int stride, cc;
    if (c < 84) { W = Wloc; stride = 84; cc = c; }
    else        { W = Wscore; stride = 21; cc = c - 84; }
    const int k0 = ks * 1024;
#pragma unroll 4
    for (int k = k0; k < k0 + 1024; ++k)
      acc = fmaf(row[k], W[(size_t)k*stride + cc], acc);
  }
  psum[ks][c] = acc;
  __syncthreads();
  if (ks == 0 && c < 105) {
    float v = psum[0][c] + psum[1][c] + psum[2][c] + psum[3][c];
    if (c < 84) out[(size_t)r*84 + c] = v + bloc[c];
    else        out[10752 + (size_t)r*21 + (c - 84)] = v + bscore[c - 84];
  }
}

// ---------------------------------------------------------------------------
extern "C" void kernel_launch(void* const* d_in, const int* in_sizes, int n_in,
                              void* d_out, int out_size, void* d_ws, size_t ws_size,
                              hipStream_t stream) {
  const float* x      = (const float*)d_in[0];
  const float* rois   = (const float*)d_in[1];
  const float* W1     = (const float*)d_in[2];
  const float* b1     = (const float*)d_in[3];
  const float* W2     = (const float*)d_in[4];
  const float* b2     = (const float*)d_in[5];
  const float* Wloc   = (const float*)d_in[6];
  const float* bloc   = (const float*)d_in[7];
  const float* Wscore = (const float*)d_in[8];
  const float* bscore = (const float*)d_in[9];
  float* out = (float*)d_out;

  char* ws = (char*)d_ws;
  __hip_bfloat16* Apool = (__hip_bfloat16*)(ws);            // 128*25088*2 = 6,422,528
  short*          fc6   = (short*)(ws + 6422528);           // 128*4096*2  = 1,048,576
  float*          part  = (float*)(ws + 9568256);           // 8*128*4096*4 = 16,777,216

  roipool_kernel<<<dim3(32, 128), 256, 0, stream>>>(x, rois, Apool);
  gemm_kernel<<<512, 256, 0, stream>>>(Apool, W1, part, 25088, 3136);
  reduce_kernel<<<512, 256, 0, stream>>>(part, b1, fc6);
  gemm_kernel<<<512, 256, 0, stream>>>((const __hip_bfloat16*)fc6, W2, part, 4096, 512);
  final_kernel<<<128, 512, 0, stream>>>(part, b2, Wloc, bloc, Wscore, bscore, out);
}

// Round 12
// 243.809 us; speedup vs baseline: 1.0513x; 1.0513x over previous
//
#include <hip/hip_runtime.h>
#include <hip/hip_bf16.h>

// ---------------------------------------------------------------------------
// R12 = R10 champion with gemm1 re-tiled for 512B B-granules:
//   gemm1: BM=128, BN=128, BK=32, split-K=16 -> grid 512 (2 blocks/CU),
//          LDS 48KB/block, acc[8][2], 16 MFMA/step. B rows read 512B/block.
//   gemm2/reduce/final/roipool byte-identical to R10 (reduce0 sums 16 now).
// Theory: gemm1 is BW-bound at 4.9 of 6.3 TB/s; 256B per-row granules are the
// suspected efficiency cap; doubling granule should lift achieved BW.
// ---------------------------------------------------------------------------

typedef __attribute__((ext_vector_type(8))) short bf16x8;
typedef __attribute__((ext_vector_type(4))) float f32x4;
typedef __attribute__((ext_vector_type(4))) short s16x4;

typedef const __attribute__((address_space(1))) void gvoid;
typedef __attribute__((address_space(3))) void lvoid;
#define GLD_LDS16(gp, lp) __builtin_amdgcn_global_load_lds((gvoid*)(gp), (lvoid*)(lp), 16, 0, 0)

#define WAITV8() { asm volatile("s_waitcnt vmcnt(8)" ::: "memory"); __builtin_amdgcn_sched_barrier(0); }
#define WAITV6() { asm volatile("s_waitcnt vmcnt(6)" ::: "memory"); __builtin_amdgcn_sched_barrier(0); }
#define WAITV0() { asm volatile("s_waitcnt vmcnt(0)" ::: "memory"); __builtin_amdgcn_sched_barrier(0); }
#define BAR() { __builtin_amdgcn_sched_barrier(0); __builtin_amdgcn_s_barrier(); __builtin_amdgcn_sched_barrier(0); }

static __device__ __forceinline__ short f2bf(float f) {   // RNE f32->bf16
  unsigned u = __builtin_bit_cast(unsigned, f);
  u += 0x7fffu + ((u >> 16) & 1u);
  return (short)(u >> 16);
}

// ---------------- K1: ROI pool -> A bf16 [128][25088] (R10 version) --------
__global__ __launch_bounds__(256) void roipool_kernel(
    const float* __restrict__ x, const float* __restrict__ rois,
    __hip_bfloat16* __restrict__ A) {
  const int cg = blockIdx.x;      // 0..31, 16 channels each
  const int r  = blockIdx.y;      // 0..127
  const float y1 = rois[r*4+0], x1 = rois[r*4+1], y2 = rois[r*4+2], x2 = rois[r*4+3];
  const int h0 = (int)(y1 * 0.0625f);
  const int h1 = (int)(y2 * 0.0625f) + 1;
  const int w0 = (int)(x1 * 0.0625f);
  const int w1 = (int)(x2 * 0.0625f) + 1;
  const int Hh = h1 - h0, Ww = w1 - w0;        // <= 17 each
  const int n = Hh * Ww;                       // <= 289
  __shared__ float tile[16][292];
  const int cl = threadIdx.x >> 4, i = threadIdx.x & 15;
  const int c = cg*16 + cl;
  const float* xc = x + c*1850 + h0*50 + w0;   // x: [512][37][50]
  for (int p = i; p < n; p += 16) {
    int rr = p / Ww, cc = p - rr*Ww;
    tile[cl][p] = xc[rr*50 + cc];
  }
  __syncthreads();
  __hip_bfloat16* Arow = A + (size_t)r*25088 + c*49;
  for (int b = i; b < 49; b += 16) {
    int hb = b / 7, wb = b - hb*7;
    int rs = (hb*Hh)/7,  re = ((hb+1)*Hh + 6)/7;
    int cs = (wb*Ww)/7,  ce = ((wb+1)*Ww + 6)/7;
    float m = -3.402823466e38f;
    for (int rr2 = rs; rr2 < re; ++rr2)
      for (int cc2 = cs; cc2 < ce; ++cc2)
        m = fmaxf(m, tile[cl][rr2*Ww + cc2]);
    Arow[b] = __float2bfloat16(m);
  }
}

// ---------------- K2: gemm1 BM=128 BN=128 BK=32 split-K=16 ------------------
// grid 512 = 16 s x 32 nb; 256 thr / 4 waves; wave w owns cols w*32..+31.
// A LDS [128][32] bf16 (64B rows), swizzle byte ^= (((row>>1)&3)<<4) -> 2-way.
// B LDS [32][128] f32 (512B rows), swizzle byte ^= ((kh&1)<<6)       -> 2-way.
__global__ __launch_bounds__(256) void gemm1_kernel(
    const __hip_bfloat16* __restrict__ A,  // [128][25088] bf16
    const float* __restrict__ B,           // [25088][4096] f32
    float* __restrict__ part) {            // [16][128][4096] f32
  __shared__ short lA[2][4096];    // 2 x 8 KB
  __shared__ float lB[2][4096];    // 2 x 16 KB
  const int t = threadIdx.x;
  const int w = t >> 6, l = t & 63;
  const int bid = blockIdx.x;
  const int s  = bid & 15;         // two K-chunks per XCD stay resident
  const int nb = bid >> 4;         // 0..31
  const int kc0 = s * 1568;
  const int Arow_bytes = 25088 * 2;

  int aoff[2], boff[4];
#pragma unroll
  for (int p = 0; p < 2; ++p) {
    int o = (p*256 + t) * 16;                 // [0,8192)
    int oa = o ^ (((o >> 7) & 3) << 4);       // inverse A swizzle (involution)
    aoff[p] = (oa >> 6) * Arow_bytes + (oa & 63);
  }
#pragma unroll
  for (int p = 0; p < 4; ++p) {
    int o = (p*256 + t) * 16;                 // [0,16384)
    int ob = o ^ (((o >> 12) & 1) << 6);      // inverse B swizzle (involution)
    boff[p] = (ob >> 9) * 16384 + (ob & 511);
  }
  const int r15 = l & 15, kh = l >> 4;
  const int axor = ((r15 >> 1) & 3) << 4;
  const int ao0 = r15*64 + ((kh*16) ^ axor);              // + mf*1024
  const int bo0 = ((kh*8)*512 + (w*32 + r15)*4)      ^ ((kh & 1) << 6);
  const int bo1 = ((kh*8)*512 + (w*32 + 16 + r15)*4) ^ ((kh & 1) << 6);

  const char* Ak = (const char*)A + kc0*2;
  const char* Bk = (const char*)B + (size_t)kc0*16384 + nb*512;

  f32x4 acc[8][2] = {};
  int cur = 0;
#pragma unroll
  for (int p = 0; p < 2; ++p)
    GLD_LDS16(Ak + aoff[p], (char*)lA[0] + (p*256 + w*64)*16);
#pragma unroll
  for (int p = 0; p < 4; ++p)
    GLD_LDS16(Bk + boff[p], (char*)lB[0] + (p*256 + w*64)*16);
  Ak += 64; Bk += (size_t)32*16384;

  for (int st = 0; st < 49; ++st) {
    if (st + 1 < 49) {
      char* dA = (char*)lA[cur ^ 1];
      char* dB = (char*)lB[cur ^ 1];
#pragma unroll
      for (int p = 0; p < 2; ++p)
        GLD_LDS16(Ak + aoff[p], dA + (p*256 + w*64)*16);
#pragma unroll
      for (int p = 0; p < 4; ++p)
        GLD_LDS16(Bk + boff[p], dB + (p*256 + w*64)*16);
      Ak += 64; Bk += (size_t)32*16384;
      WAITV6();                    // my 6 tile-st loads landed; next 6 in flight
    } else {
      WAITV0();
    }
    BAR();
    const char* lAb = (const char*)lA[cur];
    const char* lBb = (const char*)lB[cur];
    float bf0[8], bf1[8];
#pragma unroll
    for (int i2 = 0; i2 < 8; ++i2) {
      bf0[i2] = *(const float*)(lBb + bo0 + i2*512);
      bf1[i2] = *(const float*)(lBb + bo1 + i2*512);
    }
    bf16x8 bfr0, bfr1;
#pragma unroll
    for (int i2 = 0; i2 < 8; ++i2) { bfr0[i2] = f2bf(bf0[i2]); bfr1[i2] = f2bf(bf1[i2]); }
#pragma unroll
    for (int mf = 0; mf < 8; ++mf) {
      bf16x8 afrag = *(const bf16x8*)(lAb + mf*1024 + ao0);
      acc[mf][0] = __builtin_amdgcn_mfma_f32_16x16x32_bf16(afrag, bfr0, acc[mf][0], 0, 0, 0);
      acc[mf][1] = __builtin_amdgcn_mfma_f32_16x16x32_bf16(afrag, bfr1, acc[mf][1], 0, 0, 0);
    }
    BAR();
    cur ^= 1;
  }
  // C/D: col = lane&15, row = (lane>>4)*4 + q
  const int n0 = nb*128 + w*32 + r15;
  float* prow = part + (size_t)s*524288 + n0;
#pragma unroll
  for (int mf = 0; mf < 8; ++mf) {
    int m0 = mf*16 + kh*4;
#pragma unroll
    for (int q = 0; q < 4; ++q) {
      prow[(m0 + q)*4096]      = acc[mf][0][q];
      prow[(m0 + q)*4096 + 16] = acc[mf][1][q];
    }
  }
}

// ---------------- K4: gemm2 (R2/R10 body, split-K=8, BN=64, BK=64) ----------
__global__ __launch_bounds__(256) void gemm_kernel(
    const __hip_bfloat16* __restrict__ A,  // [128][K] bf16
    const float* __restrict__ B,           // [K][4096] f32
    float* __restrict__ part,              // [8][128][4096] f32
    int K, int KC) {
  __shared__ short lA[2][8192];    // 2 x 16 KB
  __shared__ float lB[2][4096];    // 2 x 16 KB
  const int t = threadIdx.x;
  const int w = t >> 6, l = t & 63;
  const int bid = blockIdx.x;
  const int s  = bid & 7;
  const int nb = bid >> 3;
  const int kc0 = s * KC;
  const int Arow_bytes = K * 2;

  int aoff[4], boff[4];
#pragma unroll
  for (int p = 0; p < 4; ++p) {
    int o = (p*256 + t) * 16;
    int oa = o ^ (((o >> 7) & 7) << 4);
    aoff[p] = (oa >> 7) * Arow_bytes + (oa & 127);
    int ob = o ^ (((o >> 11) & 1) << 6);
    boff[p] = (ob >> 8) * 16384 + (ob & 255);
  }
  const int r15 = l & 15, kh = l >> 4;
  const int xa = (r15 & 7) << 4;
  const int aoj0 = r15*128 + ((kh*16) ^ xa);
  const int aoj1 = r15*128 + (((64) + kh*16) ^ xa);
  const int bo0  = ((kh*8)*256 + (w*16 + r15)*4) ^ ((kh & 1) << 6);

  const char* Ak = (const char*)A + kc0*2;
  const char* Bk = (const char*)B + (size_t)kc0*16384 + nb*256;

  f32x4 acc[8] = {};
  const int steps = KC >> 6;
  int cur = 0;

#pragma unroll
  for (int p = 0; p < 4; ++p) {
    GLD_LDS16(Ak + aoff[p], (char*)lA[0] + (p*256 + w*64)*16);
    GLD_LDS16(Bk + boff[p], (char*)lB[0] + (p*256 + w*64)*16);
  }
  Ak += 128; Bk += 64 * 16384;

  for (int st = 0; st < steps; ++st) {
    if (st + 1 < steps) {
      char* dA = (char*)lA[cur ^ 1];
      char* dB = (char*)lB[cur ^ 1];
#pragma unroll
      for (int p = 0; p < 4; ++p) {
        GLD_LDS16(Ak + aoff[p], dA + (p*256 + w*64)*16);
        GLD_LDS16(Bk + boff[p], dB + (p*256 + w*64)*16);
      }
      Ak += 128; Bk += 64 * 16384;
      WAITV8();
    } else {
      WAITV0();
    }
    BAR();
    const char* lAb = (const char*)lA[cur];
    const char* lBb = (const char*)lB[cur];
#pragma unroll
    for (int j = 0; j < 2; ++j) {
      const int ao = j ? aoj1 : aoj0;
      const int bo = (j ? 8192 : 0) + bo0;
      float bf[8];
#pragma unroll
      for (int i2 = 0; i2 < 8; ++i2)
        bf[i2] = *(const float*)(lBb + bo + i2*256);
      bf16x8 bfrag;
#pragma unroll
      for (int i2 = 0; i2 < 8; ++i2) bfrag[i2] = f2bf(bf[i2]);
#pragma unroll
      for (int mf = 0; mf < 8; ++mf) {
        bf16x8 afrag = *(const bf16x8*)(lAb + mf*2048 + ao);
        acc[mf] = __builtin_amdgcn_mfma_f32_16x16x32_bf16(afrag, bfrag, acc[mf], 0, 0, 0);
      }
    }
    BAR();
    cur ^= 1;
  }
  const int n = nb*64 + w*16 + r15;
  float* prow = part + (size_t)s*524288 + n;
#pragma unroll
  for (int mf = 0; mf < 8; ++mf) {
    int m0 = mf*16 + kh*4;
#pragma unroll
    for (int q = 0; q < 4; ++q)
      prow[(m0 + q)*4096] = acc[mf][q];
  }
}

// ---------------- K3: reduce 16 partials + b1 + relu -> fc6 bf16 ------------
__global__ __launch_bounds__(256) void reduce_kernel(
    const float* __restrict__ part, const float* __restrict__ bias,
    short* __restrict__ outp) {
  const int idx = (blockIdx.x*256 + threadIdx.x) * 4;   // over 128*4096
  f32x4 sum = {};
#pragma unroll
  for (int s2 = 0; s2 < 16; ++s2)
    sum += *(const f32x4*)(part + (size_t)s2*524288 + idx);
  sum += *(const f32x4*)(bias + (idx & 4095));
  s16x4 o;
#pragma unroll
  for (int q = 0; q < 4; ++q) o[q] = f2bf(fmaxf(sum[q], 0.f));
  *(s16x4*)(outp + idx) = o;
}

// ---------------- K5: reduce 8 partials + b2 + relu -> row; row @ {Wloc,Wscore}
__global__ __launch_bounds__(512) void final_kernel(
    const float* __restrict__ part, const float* __restrict__ b2,
    const float* __restrict__ Wloc, const float* __restrict__ bloc,
    const float* __restrict__ Wscore, const float* __restrict__ bscore,
    float* __restrict__ out) {
  __shared__ float row[4096];
  __shared__ float psum[4][128];
  const int r = blockIdx.x, t = threadIdx.x;
  for (int ci = t; ci < 1024; ci += 512) {
    f32x4 sum = {};
#pragma unroll
    for (int s2 = 0; s2 < 8; ++s2)
      sum += *(const f32x4*)(part + (size_t)s2*524288 + r*4096 + ci*4);
    sum += *(const f32x4*)(b2 + ci*4);
    f32x4 o;
#pragma unroll
    for (int q = 0; q < 4; ++q) o[q] = fmaxf(sum[q], 0.f);
    *(f32x4*)&row[ci*4] = o;
  }
  __syncthreads();
  const int c = t & 127, ks = t >> 7;
  float acc = 0.f;
  if (c < 105) {
    const float* W; int stride, cc;
    if (c < 84) { W = Wloc; stride = 84; cc = c; }
    else        { W = Wscore; stride = 21; cc = c - 84; }
    const int k0 = ks * 1024;
#pragma unroll 4
    for (int k = k0; k < k0 + 1024; ++k)
      acc = fmaf(row[k], W[(size_t)k*stride + cc], acc);
  }
  psum[ks][c] = acc;
  __syncthreads();
  if (ks == 0 && c < 105) {
    float v = psum[0][c] + psum[1][c] + psum[2][c] + psum[3][c];
    if (c < 84) out[(size_t)r*84 + c] = v + bloc[c];
    else        out[10752 + (size_t)r*21 + (c - 84)] = v + bscore[c - 84];
  }
}

// ---------------------------------------------------------------------------
extern "C" void kernel_launch(void* const* d_in, const int* in_sizes, int n_in,
                              void* d_out, int out_size, void* d_ws, size_t ws_size,
                              hipStream_t stream) {
  const float* x      = (const float*)d_in[0];
  const float* rois   = (const float*)d_in[1];
  const float* W1     = (const float*)d_in[2];
  const float* b1     = (const float*)d_in[3];
  const float* W2     = (const float*)d_in[4];
  const float* b2     = (const float*)d_in[5];
  const float* Wloc   = (const float*)d_in[6];
  const float* bloc   = (const float*)d_in[7];
  const float* Wscore = (const float*)d_in[8];
  const float* bscore = (const float*)d_in[9];
  float* out = (float*)d_out;

  char* ws = (char*)d_ws;
  __hip_bfloat16* Apool = (__hip_bfloat16*)(ws);            // 128*25088*2 = 6,422,528
  short*          fc6   = (short*)(ws + 6422528);           // 128*4096*2  = 1,048,576
  float*          part  = (float*)(ws + 9568256);           // 16*128*4096*4 = 33,554,432

  roipool_kernel<<<dim3(32, 128), 256, 0, stream>>>(x, rois, Apool);
  gemm1_kernel<<<512, 256, 0, stream>>>(Apool, W1, part);
  reduce_kernel<<<512, 256, 0, stream>>>(part, b1, fc6);
  gemm_kernel<<<512, 256, 0, stream>>>((const __hip_bfloat16*)fc6, W2, part, 4096, 512);
  final_kernel<<<128, 512, 0, stream>>>(part, b2, Wloc, bloc, Wscore, bscore, out);
}